// Round 6
// baseline (581.980 us; speedup 1.0000x reference)
//
#include <hip/hip_runtime.h>
#include <hip/hip_bf16.h>
#include <hip/hip_fp16.h>

#define T_SEQ 4096
#define CDIM  768
#define BDIM  8
#define MROWS (BDIM * T_SEQ)   // 32768
#define NKVR  (3 * CDIM)       // 2304
#define CHL   32               // chunk length (half a raster row)
#define NCH   (T_SEQ / CHL)    // 128 chunks
#define BC    (BDIM * CDIM)    // 6144 independent recurrences

typedef __attribute__((ext_vector_type(8))) short   short8;
typedef __attribute__((ext_vector_type(4))) float   floatx4;
typedef unsigned short ushort_t;
typedef unsigned int   uint_t;

__device__ __forceinline__ ushort_t f2b(float f) {
    __hip_bfloat16 h = __float2bfloat16(f);
    return *(ushort_t*)&h;
}
__device__ __forceinline__ float b2f(ushort_t s) {
    __hip_bfloat16 h;
    *(ushort_t*)&h = s;
    return __bfloat162float(h);
}
__device__ __forceinline__ ushort_t f2h(float f) {
    __half h = __float2half(f);
    return *(ushort_t*)&h;
}
__device__ __forceinline__ float h2f(ushort_t s) {
    __half h;
    *(ushort_t*)&h = s;
    return __half2float(h);
}

__device__ __forceinline__ void gload_lds16(const void* g, void* l) {
    __builtin_amdgcn_global_load_lds(
        (const __attribute__((address_space(1))) void*)g,
        (__attribute__((address_space(3))) void*)l, 16, 0, 0);
}

// SHIFTS table: channel group i = c/32 gets shift (dy, dx); out[y][x] = in[y-dy][x-dx]
__constant__ int c_dy[24] = {0,0,1,-1,1,-1,1,-1,0,0,2,-2,2,-2,2,-2,2,1,2,1,-2,-1,-2,-1};
__constant__ int c_dx[24] = {1,-1,0,0,1,-1,-1,1,2,-2,0,0,2,-2,-2,2,1,2,-1,-2,1,2,-1,-2};

// ---------------------------------------------------------------- weights -> bf16
__global__ void cvt_weights(const float* __restrict__ kw, const float* __restrict__ vw,
                            const float* __restrict__ rw, const float* __restrict__ ow,
                            ushort_t* __restrict__ wkvr, ushort_t* __restrict__ wo) {
    int i = blockIdx.x * 256 + threadIdx.x;
    if (i < CDIM * CDIM) {
        wkvr[i]                   = f2b(kw[i]);
        wkvr[i + CDIM * CDIM]     = f2b(vw[i]);
        wkvr[i + 2 * CDIM * CDIM] = f2b(rw[i]);
        wo[i]                     = f2b(ow[i]);
    }
}

// ------------------------------------------------- shift + zigzag reorder + bf16
// 8 channels/thread (all in one shift group since 8 | 32): one bounds check,
// two float4 loads, one 16B store.
__global__ void shift_zigzag(const float* __restrict__ x, ushort_t* __restrict__ xs) {
    size_t i = (size_t)blockIdx.x * 256 + threadIdx.x;   // over MROWS*CDIM/8
    int c8 = (int)(i % (CDIM / 8)) * 8;
    size_t bt = i / (CDIM / 8);
    int tz = (int)(bt % T_SEQ);
    int b  = (int)(bt / T_SEQ);
    int r = tz >> 6, pos = tz & 63;
    int xcol = (r & 1) ? (63 - pos) : pos;
    int g = c8 >> 5;
    int ys = r - c_dy[g];
    int xsrc = xcol - c_dx[g];
    float4 v0 = {0.f, 0.f, 0.f, 0.f}, v1 = {0.f, 0.f, 0.f, 0.f};
    if ((unsigned)ys < 64u && (unsigned)xsrc < 64u) {
        const float* src = x + ((size_t)b * T_SEQ + (size_t)(ys * 64 + xsrc)) * CDIM + c8;
        v0 = *(const float4*)(src);
        v1 = *(const float4*)(src + 4);
    }
    short8 o;
    o[0] = (short)f2b(v0.x); o[1] = (short)f2b(v0.y);
    o[2] = (short)f2b(v0.z); o[3] = (short)f2b(v0.w);
    o[4] = (short)f2b(v1.x); o[5] = (short)f2b(v1.y);
    o[6] = (short)f2b(v1.z); o[7] = (short)f2b(v1.w);
    *(short8*)(xs + bt * CDIM + c8) = o;
}

// ---------------------------------------------------------------- bf16 MFMA GEMM
// PROVEN structure (r3: 134.6us, MfmaUtil 39%, occ 37%, conflicts 0):
// 128x128 tile, BK=64, 256 thr, 3 blocks/CU. (8-phase 256^2 regressed, r2.)
// r6: MODE 0 epilogue writes kb/vb/srb in T-MAJOR layout [b][c][t]
// (offset (b*CDIM+c)*T_SEQ + t): each thread's 4 r-values are consecutive t
// -> one packed 8B store per (mi,ni). Lines fully covered per block (t-range
// 128 contiguous per channel). WKV kernels then read 16B-contiguous chunks.
// MODE 0 (NB=18): nb/6==0 -> k (fp16), ==1 -> v (fp16), ==2 -> sigmoid(r) bf16.
// MODE 1 (NB=6): fp32 out, [row][c] layout.
template <int MODE, int NB>
__device__ __forceinline__ void gemm_body(
    const ushort_t* __restrict__ A, const ushort_t* __restrict__ Bw,
    ushort_t* __restrict__ kbuf, ushort_t* __restrict__ vbuf,
    ushort_t* __restrict__ srbuf, float* __restrict__ out_f) {
    __shared__ ushort_t As[128 * 64];
    __shared__ ushort_t Bs[128 * 64];
    const int p    = blockIdx.x;
    const int xcd  = p & 7;
    const int s    = p >> 3;
    const int mb   = xcd + 8 * (s / NB);
    const int nb   = s % NB;
    const int m0   = mb * 128;
    const int n0   = nb * 128;
    const int t    = threadIdx.x;
    const int lane = t & 63;
    const int wv   = t >> 6;
    const int wm   = (wv & 1) * 64;
    const int wn   = (wv >> 1) * 64;
    const int srow = t >> 3;   // 0..31
    const int sch  = t & 7;    // lds slot chunk
    const int l15  = lane & 15;
    const int l4   = lane >> 4;

    floatx4 acc[4][4];
#pragma unroll
    for (int i = 0; i < 4; i++)
#pragma unroll
        for (int j = 0; j < 4; j++) acc[i][j] = (floatx4){0.f, 0.f, 0.f, 0.f};

    for (int kk = 0; kk < CDIM; kk += 64) {
        __syncthreads();
#pragma unroll
        for (int j = 0; j < 4; j++) {
            const int rowA = 32 * j + srow;
            const int gc   = sch ^ (rowA & 7);
            gload_lds16(A  + (size_t)(m0 + rowA) * CDIM + kk + gc * 8,
                        (void*)(As + j * 2048 + t * 8));
            gload_lds16(Bw + (size_t)(n0 + rowA) * CDIM + kk + gc * 8,
                        (void*)(Bs + j * 2048 + t * 8));
        }
        __syncthreads();
#pragma unroll
        for (int k2 = 0; k2 < 2; k2++) {
            short8 af[4], bfv[4];
#pragma unroll
            for (int mi = 0; mi < 4; mi++) {
                int ra = wm + mi * 16 + l15;
                int c  = k2 * 4 + l4;
                af[mi] = *(const short8*)(As + ra * 64 + ((c ^ (ra & 7)) << 3));
            }
#pragma unroll
            for (int ni = 0; ni < 4; ni++) {
                int rb = wn + ni * 16 + l15;
                int c  = k2 * 4 + l4;
                bfv[ni] = *(const short8*)(Bs + rb * 64 + ((c ^ (rb & 7)) << 3));
            }
#pragma unroll
            for (int mi = 0; mi < 4; mi++)
#pragma unroll
                for (int ni = 0; ni < 4; ni++)
                    acc[mi][ni] = __builtin_amdgcn_mfma_f32_16x16x32_bf16(
                        af[mi], bfv[ni], acc[mi][ni], 0, 0, 0);
        }
    }

    if (MODE == 0) {
        const int region = nb / 6;
        const int ncb = n0 - region * CDIM;
        const int bidx = mb >> 5;              // batch
        const int tt   = (mb & 31) * 128;      // t-base of this m-tile
        ushort_t* plane = (region == 0) ? kbuf : (region == 1) ? vbuf : srbuf;
#pragma unroll
        for (int mi = 0; mi < 4; mi++) {
#pragma unroll
            for (int ni = 0; ni < 4; ni++) {
                const int nc = ncb + wn + ni * 16 + l15;
                const int t0 = tt + wm + mi * 16 + l4 * 4;
                uint_t lo, hi;
                if (region == 2) {
                    lo = (uint_t)f2b(1.0f / (1.0f + __expf(-acc[mi][ni][0]))) |
                         ((uint_t)f2b(1.0f / (1.0f + __expf(-acc[mi][ni][1]))) << 16);
                    hi = (uint_t)f2b(1.0f / (1.0f + __expf(-acc[mi][ni][2]))) |
                         ((uint_t)f2b(1.0f / (1.0f + __expf(-acc[mi][ni][3]))) << 16);
                } else {
                    lo = (uint_t)f2h(acc[mi][ni][0]) | ((uint_t)f2h(acc[mi][ni][1]) << 16);
                    hi = (uint_t)f2h(acc[mi][ni][2]) | ((uint_t)f2h(acc[mi][ni][3]) << 16);
                }
                uint2 pk = make_uint2(lo, hi);
                *(uint2*)(plane + ((size_t)bidx * CDIM + nc) * T_SEQ + t0) = pk;
            }
        }
    } else {
#pragma unroll
        for (int mi = 0; mi < 4; mi++) {
#pragma unroll
            for (int ni = 0; ni < 4; ni++) {
                const int nc = n0 + wn + ni * 16 + l15;
#pragma unroll
                for (int r = 0; r < 4; r++) {
                    const int mg = m0 + wm + mi * 16 + l4 * 4 + r;
                    out_f[(size_t)mg * CDIM + nc] = acc[mi][ni][r];
                }
            }
        }
    }
}

__global__ __launch_bounds__(256, 3) void gemm_kvr(
    const ushort_t* __restrict__ A, const ushort_t* __restrict__ Bw,
    ushort_t* __restrict__ kbuf, ushort_t* __restrict__ vbuf,
    ushort_t* __restrict__ srbuf) {
    gemm_body<0, 18>(A, Bw, kbuf, vbuf, srbuf, nullptr);
}

__global__ __launch_bounds__(256, 3) void gemm_out(
    const ushort_t* __restrict__ A, const ushort_t* __restrict__ Bw,
    float* __restrict__ out_f) {
    gemm_body<1, 6>(A, Bw, nullptr, nullptr, nullptr, out_f);
}

// ------------------------------------------------------------- WKV chunked scan
// kb / vb / srb: T-MAJOR fp16/bf16 planes, offset (b*CDIM+c)*T_SEQ + t
// (t = zigzag sequence index). Summary arrays: [bc][NCH].
// Each thread loads its 32-element chunk as 4 x 16B contiguous loads; all
// register arrays statically indexed (rule #20: rev-branches are uniform and
// fully unrolled — the old runtime-index pass-2 went to scratch).
// PASS 0 sequence = zigzag order (t). PASS 1 = raster order; pass-1 chunk ch
// covers the CONTIGUOUS t-window [t_lo, t_lo+32), t_lo = r*64 + (r&1 ? 32-pos0
// : pos0), traversed in reverse iff r odd. Pass-1 chunk ch maps to pass-2
// chunk idx2 = (ch&2) ? ch^1 : ch (verified).

// Phase A (pass 0): per-chunk local summary. Lanes = consecutive ch of one
// (b,c) column -> 1KB contiguous loads, coalesced summary writes.
__global__ __launch_bounds__(256) void wkv_chunk_sum0(
    const ushort_t* __restrict__ kb, const ushort_t* __restrict__ vb,
    const float* __restrict__ sd,
    float* __restrict__ sumP, float* __restrict__ sumQ, float* __restrict__ sumO) {
    int gid = blockIdx.x * 256 + threadIdx.x;   // over BC*NCH, ch fastest
    int ch = gid & (NCH - 1);
    int bc = gid >> 7;
    int c = bc % CDIM;
    const float w = sd[c] * (1.0f / (float)T_SEQ);
    const short8* kp = (const short8*)(kb + (size_t)bc * T_SEQ + ch * CHL);
    const short8* vp = (const short8*)(vb + (size_t)bc * T_SEQ + ch * CHL);
    short8 ks[4], vs[4];
#pragma unroll
    for (int r = 0; r < 4; r++) { ks[r] = kp[r]; vs[r] = vp[r]; }
    float p = 0.f, q = 0.f, o = -1e38f;
#pragma unroll
    for (int i = 0; i < CHL; i++) {
        float kt = h2f((ushort_t)ks[i >> 3][i & 7]);
        float vt = h2f((ushort_t)vs[i >> 3][i & 7]);
        float wo_ = w + o;
        float no2 = fmaxf(wo_, kt);
        float A2 = __expf(wo_ - no2), B2 = __expf(kt - no2);
        p = A2 * p + B2 * vt;
        q = A2 * q + B2;
        o = no2;
    }
    size_t idx = (size_t)bc * NCH + ch;
    sumP[idx] = p; sumQ[idx] = q; sumO[idx] = o;
}

// Phase B: sequential combine; each lane streams its own [NCH] row.
__global__ __launch_bounds__(256) void wkv_chunk_scan(
    const float* __restrict__ sumP, const float* __restrict__ sumQ,
    const float* __restrict__ sumO,
    float* __restrict__ inP, float* __restrict__ inQ, float* __restrict__ inO,
    const float* __restrict__ sd, int pass) {
    int bc = blockIdx.x * 256 + threadIdx.x;
    if (bc >= BC) return;
    int c = bc % CDIM;
    const float w = sd[pass * CDIM + c] * (1.0f / (float)T_SEQ);
    const float Lw = w * (float)CHL;
    const float* sp = sumP + (size_t)bc * NCH;
    const float* sq = sumQ + (size_t)bc * NCH;
    const float* so = sumO + (size_t)bc * NCH;
    float* ip = inP + (size_t)bc * NCH;
    float* iq = inQ + (size_t)bc * NCH;
    float* io = inO + (size_t)bc * NCH;
    float p = 0.f, q = 0.f, o = -1e38f;
#pragma unroll 4
    for (int ch = 0; ch < NCH; ch++) {
        ip[ch] = p; iq[ch] = q; io[ch] = o;
        float Pc = sp[ch], Qc = sq[ch], Oc = so[ch];
        float ow_ = o + Lw;
        float no = fmaxf(ow_, Oc);
        float e1 = __expf(ow_ - no), e2 = __expf(Oc - no);
        p = e1 * p + e2 * Pc;
        q = e1 * q + e2 * Qc;
        o = no;
    }
}

// Phase C fused: replay pass-0 chunk (y -> vb, 4x16B stores; k/y in true
// registers), then pass-2 summary over the same rows in raster traversal.
// Lanes = consecutive bc (ch block-uniform -> rev branches uniform).
__global__ __launch_bounds__(256) void wkv_replay0_sum1(
    const ushort_t* __restrict__ kb, ushort_t* __restrict__ vb,
    const float* __restrict__ sd, const float* __restrict__ sf,
    const float* __restrict__ inP, const float* __restrict__ inQ,
    const float* __restrict__ inO,
    float* __restrict__ sumP, float* __restrict__ sumQ, float* __restrict__ sumO) {
    int gid = blockIdx.x * 256 + threadIdx.x;   // over BC*NCH, bc fastest
    int bc = gid % BC;
    int ch = gid / BC;                           // block-uniform (BC % 256 == 0)
    int c = bc % CDIM;
    const float w1 = sd[c] * (1.0f / (float)T_SEQ);
    const float u1 = sf[c] * (1.0f / (float)T_SEQ);
    const size_t base = (size_t)bc * T_SEQ + ch * CHL;
    const short8* kp = (const short8*)(kb + base);
    short8* vp = (short8*)(vb + base);
    short8 ks[4], vs[4], ys[4];
#pragma unroll
    for (int r = 0; r < 4; r++) { ks[r] = kp[r]; vs[r] = vp[r]; }
    size_t sidx = (size_t)bc * NCH + ch;
    float p = inP[sidx], q = inQ[sidx], o = inO[sidx];
#pragma unroll
    for (int i = 0; i < CHL; i++) {
        float kt = h2f((ushort_t)ks[i >> 3][i & 7]);
        float vt = h2f((ushort_t)vs[i >> 3][i & 7]);
        float uk = u1 + kt;
        float no = fmaxf(o, uk);
        float Ae = __expf(o - no), Be = __expf(uk - no);
        float y = (Ae * p + Be * vt) / (Ae * q + Be);
        float wo_ = w1 + o;
        float no2 = fmaxf(wo_, kt);
        float A2 = __expf(wo_ - no2), B2 = __expf(kt - no2);
        p = A2 * p + B2 * vt;
        q = A2 * q + B2;
        o = no2;
        ys[i >> 3][i & 7] = (short)f2h(y);
    }
#pragma unroll
    for (int r = 0; r < 4; r++) vp[r] = ys[r];   // overwrite v with y
    // pass-2 summary over same rows; raster traversal uses fp16-rounded y.
    const float w2 = sd[CDIM + c] * (1.0f / (float)T_SEQ);
    float p2 = 0.f, q2 = 0.f, o2 = -1e38f;
#define P2STEP(IDX)                                                         \
    {                                                                       \
        float kt = h2f((ushort_t)ks[(IDX) >> 3][(IDX) & 7]);                \
        float yt = h2f((ushort_t)ys[(IDX) >> 3][(IDX) & 7]);                \
        float wo_ = w2 + o2;                                                \
        float nn = fmaxf(wo_, kt);                                          \
        float A2 = __expf(wo_ - nn), B2 = __expf(kt - nn);                  \
        p2 = A2 * p2 + B2 * yt;                                             \
        q2 = A2 * q2 + B2;                                                  \
        o2 = nn;                                                            \
    }
    if (((ch >> 1) & 1) == 0) {
#pragma unroll
        for (int j = 0; j < CHL; j++) P2STEP(j)
    } else {
#pragma unroll
        for (int j = 0; j < CHL; j++) P2STEP(CHL - 1 - j)
    }
#undef P2STEP
    int idx2 = (ch & 2) ? (ch ^ 1) : ch;
    size_t oidx = (size_t)bc * NCH + idx2;
    sumP[oidx] = p2; sumQ[oidx] = q2; sumO[oidx] = o2;
}

// Phase C (pass 1): replay raster-order chunk ch, emit a2 = bf16(y * sr) in
// [row][c] layout for the output GEMM. Lanes = consecutive bc -> a2 writes
// 128B-contiguous; k/v/sr loads are full-line per-lane gathers.
__global__ __launch_bounds__(256) void wkv_replay1(
    const ushort_t* __restrict__ kb, const ushort_t* __restrict__ vb,
    const ushort_t* __restrict__ srb, ushort_t* __restrict__ a2,
    const float* __restrict__ sd, const float* __restrict__ sf,
    const float* __restrict__ inP, const float* __restrict__ inQ,
    const float* __restrict__ inO) {
    int gid = blockIdx.x * 256 + threadIdx.x;   // over BC*NCH, bc fastest
    int bc = gid % BC;
    int ch = gid / BC;                           // block-uniform
    int b = bc / CDIM, c = bc % CDIM;
    const float w = sd[CDIM + c] * (1.0f / (float)T_SEQ);
    const float u = sf[CDIM + c] * (1.0f / (float)T_SEQ);
    const int r = ch >> 1;
    const int pos0 = (ch & 1) * CHL;
    const int t_lo = r * 64 + ((r & 1) ? (CHL - pos0) : pos0);
    const size_t base = (size_t)bc * T_SEQ + t_lo;
    const short8* kp = (const short8*)(kb + base);
    const short8* vp = (const short8*)(vb + base);
    const short8* sp = (const short8*)(srb + base);
    short8 ks[4], vs[4], ss[4];
#pragma unroll
    for (int rr = 0; rr < 4; rr++) { ks[rr] = kp[rr]; vs[rr] = vp[rr]; ss[rr] = sp[rr]; }
    size_t sidx = (size_t)bc * NCH + ch;
    float p = inP[sidx], q = inQ[sidx], o = inO[sidx];
    ushort_t* aout = a2 + ((size_t)b * T_SEQ + t_lo) * CDIM + c;
#define R1STEP(E)                                                           \
    {                                                                       \
        float kt = h2f((ushort_t)ks[(E) >> 3][(E) & 7]);                    \
        float vt = h2f((ushort_t)vs[(E) >> 3][(E) & 7]);                    \
        float uk = u + kt;                                                  \
        float no = fmaxf(o, uk);                                            \
        float Ae = __expf(o - no), Be = __expf(uk - no);                    \
        float y = (Ae * p + Be * vt) / (Ae * q + Be);                       \
        float wo_ = w + o;                                                  \
        float nn = fmaxf(wo_, kt);                                          \
        float A2 = __expf(wo_ - nn), B2 = __expf(kt - nn);                  \
        p = A2 * p + B2 * vt;                                               \
        q = A2 * q + B2;                                                    \
        o = nn;                                                             \
        aout[(size_t)(E) * CDIM] =                                          \
            f2b(y * b2f((ushort_t)ss[(E) >> 3][(E) & 7]));                  \
    }
    if ((r & 1) == 0) {
#pragma unroll
        for (int j = 0; j < CHL; j++) R1STEP(j)
    } else {
#pragma unroll
        for (int j = 0; j < CHL; j++) R1STEP(CHL - 1 - j)
    }
#undef R1STEP
}

// ----------------------------------------------------------------------- launch
extern "C" void kernel_launch(void* const* d_in, const int* in_sizes, int n_in,
                              void* d_out, int out_size, void* d_ws, size_t ws_size,
                              hipStream_t stream) {
    (void)in_sizes; (void)n_in; (void)out_size; (void)ws_size;
    const float* x  = (const float*)d_in[0];
    const float* kw = (const float*)d_in[1];
    const float* vw = (const float*)d_in[2];
    const float* rw = (const float*)d_in[3];
    const float* ow = (const float*)d_in[4];
    const float* sd = (const float*)d_in[5];
    const float* sf = (const float*)d_in[6];
    float* out = (float*)d_out;

    char* ws = (char*)d_ws;
    size_t off = 0;
    auto alloc = [&](size_t bytes) -> void* {
        void* p = ws + off;
        off += (bytes + 255) & ~(size_t)255;
        return p;
    };
    ushort_t* xs   = (ushort_t*)alloc((size_t)MROWS * CDIM * 2);  // reused as a2
    ushort_t* kb   = (ushort_t*)alloc((size_t)MROWS * CDIM * 2);  // k fp16 T-major
    ushort_t* vb   = (ushort_t*)alloc((size_t)MROWS * CDIM * 2);  // v/y fp16 T-major
    ushort_t* srb  = (ushort_t*)alloc((size_t)MROWS * CDIM * 2);  // bf16 T-major
    ushort_t* wkvr = (ushort_t*)alloc((size_t)NKVR * CDIM * 2);
    ushort_t* wo   = (ushort_t*)alloc((size_t)CDIM * CDIM * 2);
    float*    sumP = (float*)   alloc((size_t)NCH * BC * 4);
    float*    sumQ = (float*)   alloc((size_t)NCH * BC * 4);
    float*    sumO = (float*)   alloc((size_t)NCH * BC * 4);
    float*    inP  = (float*)   alloc((size_t)NCH * BC * 4);
    float*    inQ  = (float*)   alloc((size_t)NCH * BC * 4);
    float*    inO  = (float*)   alloc((size_t)NCH * BC * 4);

    cvt_weights<<<(CDIM * CDIM + 255) / 256, 256, 0, stream>>>(kw, vw, rw, ow, wkvr, wo);
    shift_zigzag<<<(int)((size_t)MROWS * (CDIM / 8) / 256), 256, 0, stream>>>(x, xs);
    gemm_kvr<<<(MROWS / 128) * (NKVR / 128), 256, 0, stream>>>(
        xs, wkvr, kb, vb, srb);

    const int nwkv = NCH * BC;  // 786432 threads
    wkv_chunk_sum0<<<nwkv / 256, 256, 0, stream>>>(kb, vb, sd, sumP, sumQ, sumO);
    wkv_chunk_scan<<<(BC + 255) / 256, 256, 0, stream>>>(sumP, sumQ, sumO,
                                                         inP, inQ, inO, sd, 0);
    wkv_replay0_sum1<<<nwkv / 256, 256, 0, stream>>>(kb, vb, sd, sf,
                                                     inP, inQ, inO, sumP, sumQ, sumO);
    wkv_chunk_scan<<<(BC + 255) / 256, 256, 0, stream>>>(sumP, sumQ, sumO,
                                                         inP, inQ, inO, sd, 1);
    wkv_replay1<<<nwkv / 256, 256, 0, stream>>>(kb, vb, srb, xs,
                                                sd, sf, inP, inQ, inO);

    gemm_out<<<(MROWS / 128) * (CDIM / 128), 256, 0, stream>>>(xs, wo, out);
}

// Round 7
// 523.074 us; speedup vs baseline: 1.1126x; 1.1126x over previous
//
#include <hip/hip_runtime.h>
#include <hip/hip_bf16.h>
#include <hip/hip_fp16.h>

#define T_SEQ 4096
#define CDIM  768
#define BDIM  8
#define MROWS (BDIM * T_SEQ)   // 32768
#define NKVR  (3 * CDIM)       // 2304
#define CHL   32               // chunk length (half a raster row)
#define NCH   (T_SEQ / CHL)    // 128 chunks
#define BC    (BDIM * CDIM)    // 6144 independent recurrences
#define BC2   (BC / 2)         // 3072 channel-pairs
#define CD2   (CDIM / 2)       // 384

typedef __attribute__((ext_vector_type(8))) short   short8;
typedef __attribute__((ext_vector_type(4))) float   floatx4;
typedef unsigned short ushort_t;
typedef unsigned int   uint_t;

__device__ __forceinline__ ushort_t f2b(float f) {
    __hip_bfloat16 h = __float2bfloat16(f);
    return *(ushort_t*)&h;
}
__device__ __forceinline__ float b2f(ushort_t s) {
    __hip_bfloat16 h;
    *(ushort_t*)&h = s;
    return __bfloat162float(h);
}
__device__ __forceinline__ ushort_t f2h(float f) {
    __half h = __float2half(f);
    return *(ushort_t*)&h;
}
__device__ __forceinline__ float h2f(ushort_t s) {
    __half h;
    *(ushort_t*)&h = s;
    return __half2float(h);
}

__device__ __forceinline__ void gload_lds16(const void* g, void* l) {
    __builtin_amdgcn_global_load_lds(
        (const __attribute__((address_space(1))) void*)g,
        (__attribute__((address_space(3))) void*)l, 16, 0, 0);
}

// SHIFTS table: channel group i = c/32 gets shift (dy, dx); out[y][x] = in[y-dy][x-dx]
__constant__ int c_dy[24] = {0,0,1,-1,1,-1,1,-1,0,0,2,-2,2,-2,2,-2,2,1,2,1,-2,-1,-2,-1};
__constant__ int c_dx[24] = {1,-1,0,0,1,-1,-1,1,2,-2,0,0,2,-2,-2,2,1,2,-1,-2,1,2,-1,-2};

// ---------------------------------------------------------------- weights -> bf16
__global__ void cvt_weights(const float* __restrict__ kw, const float* __restrict__ vw,
                            const float* __restrict__ rw, const float* __restrict__ ow,
                            ushort_t* __restrict__ wkvr, ushort_t* __restrict__ wo) {
    int i = blockIdx.x * 256 + threadIdx.x;
    if (i < CDIM * CDIM) {
        wkvr[i]                   = f2b(kw[i]);
        wkvr[i + CDIM * CDIM]     = f2b(vw[i]);
        wkvr[i + 2 * CDIM * CDIM] = f2b(rw[i]);
        wo[i]                     = f2b(ow[i]);
    }
}

// ------------------------------------------------- shift + zigzag reorder + bf16
// 8 channels/thread (all in one shift group since 8 | 32): one bounds check,
// two float4 loads, one 16B store.
__global__ void shift_zigzag(const float* __restrict__ x, ushort_t* __restrict__ xs) {
    size_t i = (size_t)blockIdx.x * 256 + threadIdx.x;   // over MROWS*CDIM/8
    int c8 = (int)(i % (CDIM / 8)) * 8;
    size_t bt = i / (CDIM / 8);
    int tz = (int)(bt % T_SEQ);
    int b  = (int)(bt / T_SEQ);
    int r = tz >> 6, pos = tz & 63;
    int xcol = (r & 1) ? (63 - pos) : pos;
    int g = c8 >> 5;
    int ys = r - c_dy[g];
    int xsrc = xcol - c_dx[g];
    float4 v0 = {0.f, 0.f, 0.f, 0.f}, v1 = {0.f, 0.f, 0.f, 0.f};
    if ((unsigned)ys < 64u && (unsigned)xsrc < 64u) {
        const float* src = x + ((size_t)b * T_SEQ + (size_t)(ys * 64 + xsrc)) * CDIM + c8;
        v0 = *(const float4*)(src);
        v1 = *(const float4*)(src + 4);
    }
    short8 o;
    o[0] = (short)f2b(v0.x); o[1] = (short)f2b(v0.y);
    o[2] = (short)f2b(v0.z); o[3] = (short)f2b(v0.w);
    o[4] = (short)f2b(v1.x); o[5] = (short)f2b(v1.y);
    o[6] = (short)f2b(v1.z); o[7] = (short)f2b(v1.w);
    *(short8*)(xs + bt * CDIM + c8) = o;
}

// ---------------------------------------------------------------- bf16 MFMA GEMM
// PROVEN structure (r3: 134.6us, MfmaUtil 39%, occ 37%, conflicts 0):
// 128x128 tile, BK=64, 256 thr, 3 blocks/CU. (8-phase 256^2 regressed, r2;
// T-major epilogue regressed via partial-line RMW, r6: FETCH+WRITE both +30MB.)
// kb/vb/srb are [t][c] planes — lane=c coalescing for all consumers.
// XCD swizzle: all NB n-blocks of an m-strip share one XCD (L2-hot A + W).
// Staging: thread t loads global chunk gc = (t&7)^(row&7) into LDS slot t&7
// (global_load_lds requires lane-contiguous LDS dest); reads un-swizzle ->
// 2-way bank aliasing (free).
// MODE 0 (NB=18): nb/6==0 -> k (fp16), ==1 -> v (fp16), ==2 -> sigmoid(r) bf16.
// MODE 1 (NB=6): fp32 out.
template <int MODE, int NB>
__device__ __forceinline__ void gemm_body(
    const ushort_t* __restrict__ A, const ushort_t* __restrict__ Bw,
    ushort_t* __restrict__ kbuf, ushort_t* __restrict__ vbuf,
    ushort_t* __restrict__ out_sr, float* __restrict__ out_f) {
    __shared__ ushort_t As[128 * 64];
    __shared__ ushort_t Bs[128 * 64];
    const int p    = blockIdx.x;
    const int xcd  = p & 7;
    const int s    = p >> 3;
    const int mb   = xcd + 8 * (s / NB);
    const int nb   = s % NB;
    const int m0   = mb * 128;
    const int n0   = nb * 128;
    const int t    = threadIdx.x;
    const int lane = t & 63;
    const int wv   = t >> 6;
    const int wm   = (wv & 1) * 64;
    const int wn   = (wv >> 1) * 64;
    const int srow = t >> 3;   // 0..31
    const int sch  = t & 7;    // lds slot chunk
    const int l15  = lane & 15;
    const int l4   = lane >> 4;

    floatx4 acc[4][4];
#pragma unroll
    for (int i = 0; i < 4; i++)
#pragma unroll
        for (int j = 0; j < 4; j++) acc[i][j] = (floatx4){0.f, 0.f, 0.f, 0.f};

    for (int kk = 0; kk < CDIM; kk += 64) {
        __syncthreads();
#pragma unroll
        for (int j = 0; j < 4; j++) {
            const int rowA = 32 * j + srow;
            const int gc   = sch ^ (rowA & 7);
            gload_lds16(A  + (size_t)(m0 + rowA) * CDIM + kk + gc * 8,
                        (void*)(As + j * 2048 + t * 8));
            gload_lds16(Bw + (size_t)(n0 + rowA) * CDIM + kk + gc * 8,
                        (void*)(Bs + j * 2048 + t * 8));
        }
        __syncthreads();
#pragma unroll
        for (int k2 = 0; k2 < 2; k2++) {
            short8 af[4], bfv[4];
#pragma unroll
            for (int mi = 0; mi < 4; mi++) {
                int ra = wm + mi * 16 + l15;
                int c  = k2 * 4 + l4;
                af[mi] = *(const short8*)(As + ra * 64 + ((c ^ (ra & 7)) << 3));
            }
#pragma unroll
            for (int ni = 0; ni < 4; ni++) {
                int rb = wn + ni * 16 + l15;
                int c  = k2 * 4 + l4;
                bfv[ni] = *(const short8*)(Bs + rb * 64 + ((c ^ (rb & 7)) << 3));
            }
#pragma unroll
            for (int mi = 0; mi < 4; mi++)
#pragma unroll
                for (int ni = 0; ni < 4; ni++)
                    acc[mi][ni] = __builtin_amdgcn_mfma_f32_16x16x32_bf16(
                        af[mi], bfv[ni], acc[mi][ni], 0, 0, 0);
        }
    }

    const int region = (MODE == 0) ? (nb / 6) : 0;
    const int ncb = n0 - region * CDIM;
#pragma unroll
    for (int mi = 0; mi < 4; mi++) {
#pragma unroll
        for (int ni = 0; ni < 4; ni++) {
            int nc = ncb + wn + ni * 16 + l15;
#pragma unroll
            for (int r = 0; r < 4; r++) {
                int mg = m0 + wm + mi * 16 + l4 * 4 + r;
                float val = acc[mi][ni][r];
                if (MODE == 0) {
                    if (region == 0)
                        kbuf[(size_t)mg * CDIM + nc] = f2h(val);
                    else if (region == 1)
                        vbuf[(size_t)mg * CDIM + nc] = f2h(val);
                    else
                        out_sr[(size_t)mg * CDIM + nc] =
                            f2b(1.0f / (1.0f + __expf(-val)));
                } else {
                    out_f[(size_t)mg * CDIM + (n0 + wn + ni * 16 + l15)] = val;
                }
            }
        }
    }
}

__global__ __launch_bounds__(256, 3) void gemm_kvr(
    const ushort_t* __restrict__ A, const ushort_t* __restrict__ Bw,
    ushort_t* __restrict__ kbuf, ushort_t* __restrict__ vbuf,
    ushort_t* __restrict__ out_sr) {
    gemm_body<0, 18>(A, Bw, kbuf, vbuf, out_sr, nullptr);
}

__global__ __launch_bounds__(256, 3) void gemm_out(
    const ushort_t* __restrict__ A, const ushort_t* __restrict__ Bw,
    float* __restrict__ out_f) {
    gemm_body<1, 6>(A, Bw, nullptr, nullptr, nullptr, out_f);
}

// ------------------------------------------------------------- WKV chunked scan
// Recurrence: P' = e^w P + e^k v ; state max-normalized as (p,q,o).
// kb / vb: separate fp16 [t][c] planes. vb overwritten with y by pass-0 replay.
// PASS 0 sequence = zigzag row order (buffer row order).
// PASS 1 sequence = raster order; CHL=32 chunk remap (verified):
//   pass-1 chunk ch's rows form pass-2 chunk idx2 = (ch&2) ? ch^1 : ch,
//   traversed in reverse iff (ch>>1)&1.
// 2 adjacent channels/thread via packed-fp16 uint loads (G13). replay0_sum1
// register arrays PACKED as uint (64 VGPR) and — r7 fix — pass-2 statically
// indexed via uniform-rev branch with two fully-unrolled loops (rule #20: the
// old runtime index i = rev ? 31-j : j demoted ku_/yu_ to scratch).
// ch = gid / BC2 is block-uniform (BC2 % 256 == 0) -> branch non-divergent.

// Phase A (pass 0): per-chunk local summary from empty state. 2 ch/thread.
__global__ __launch_bounds__(256) void wkv_chunk_sum0(
    const ushort_t* __restrict__ kb, const ushort_t* __restrict__ vb,
    const float* __restrict__ sd,
    float* __restrict__ sumP, float* __restrict__ sumQ, float* __restrict__ sumO) {
    int gid = blockIdx.x * 256 + threadIdx.x;   // over NCH*BC2
    int bc2 = gid % BC2;
    int ch  = gid / BC2;
    int b = bc2 / CD2, cp = (bc2 % CD2) * 2;
    const float w0 = sd[cp]     * (1.0f / (float)T_SEQ);
    const float w1 = sd[cp + 1] * (1.0f / (float)T_SEQ);
    const size_t base = ((size_t)b * T_SEQ + ch * CHL) * CDIM + cp;
    const uint_t* kp = (const uint_t*)(kb + base);
    const uint_t* vp = (const uint_t*)(vb + base);
    float p0 = 0.f, q0 = 0.f, o0 = -1e38f;
    float p1 = 0.f, q1 = 0.f, o1 = -1e38f;
#pragma unroll 8
    for (int i = 0; i < CHL; i++) {
        uint_t ku = kp[(size_t)i * CD2], vu = vp[(size_t)i * CD2];
        float k0 = h2f((ushort_t)(ku & 0xffff)), k1 = h2f((ushort_t)(ku >> 16));
        float v0 = h2f((ushort_t)(vu & 0xffff)), v1 = h2f((ushort_t)(vu >> 16));
        float wo0 = w0 + o0, wo1 = w1 + o1;
        float n0_ = fmaxf(wo0, k0), n1_ = fmaxf(wo1, k1);
        float A0 = __expf(wo0 - n0_), B0 = __expf(k0 - n0_);
        float A1 = __expf(wo1 - n1_), B1 = __expf(k1 - n1_);
        p0 = A0 * p0 + B0 * v0;  q0 = A0 * q0 + B0;  o0 = n0_;
        p1 = A1 * p1 + B1 * v1;  q1 = A1 * q1 + B1;  o1 = n1_;
    }
    size_t idx = (size_t)ch * BC + (size_t)b * CDIM + cp;   // even -> 8B aligned
    *(float2*)(sumP + idx) = make_float2(p0, p1);
    *(float2*)(sumQ + idx) = make_float2(q0, q1);
    *(float2*)(sumO + idx) = make_float2(o0, o1);
}

// Phase B: sequential combine of chunk summaries; writes incoming state per chunk.
__global__ __launch_bounds__(256) void wkv_chunk_scan(
    const float* __restrict__ sumP, const float* __restrict__ sumQ,
    const float* __restrict__ sumO,
    float* __restrict__ inP, float* __restrict__ inQ, float* __restrict__ inO,
    const float* __restrict__ sd, int pass) {
    int bc = blockIdx.x * 256 + threadIdx.x;
    if (bc >= BC) return;
    int c = bc % CDIM;
    const float w = sd[pass * CDIM + c] * (1.0f / (float)T_SEQ);
    const float Lw = w * (float)CHL;
    float p = 0.f, q = 0.f, o = -1e38f;
#pragma unroll 4
    for (int ch = 0; ch < NCH; ch++) {
        size_t idx = (size_t)ch * BC + bc;
        inP[idx] = p; inQ[idx] = q; inO[idx] = o;
        float Pc = sumP[idx], Qc = sumQ[idx], Oc = sumO[idx];
        float ow_ = o + Lw;
        float no = fmaxf(ow_, Oc);
        float e1 = __expf(ow_ - no), e2 = __expf(Oc - no);
        p = e1 * p + e2 * Pc;
        q = e1 * q + e2 * Qc;
        o = no;
    }
}

// Phase C fused: replay pass-0 chunk (y -> vb packed 4B stores, k/y kept in
// PACKED uint registers, FULLY unrolled), then pass-2 chunk summary over the
// same rows in raster traversal. 2 ch/thread. Pass-2 statically indexed.
__global__ __launch_bounds__(256) void wkv_replay0_sum1(
    const ushort_t* __restrict__ kb, ushort_t* __restrict__ vb,
    const float* __restrict__ sd, const float* __restrict__ sf,
    const float* __restrict__ inP, const float* __restrict__ inQ,
    const float* __restrict__ inO,
    float* __restrict__ sumP, float* __restrict__ sumQ, float* __restrict__ sumO) {
    int gid = blockIdx.x * 256 + threadIdx.x;   // over NCH*BC2
    int bc2 = gid % BC2;
    int ch  = gid / BC2;                         // block-uniform
    int b = bc2 / CD2, cp = (bc2 % CD2) * 2;
    const float w10 = sd[cp]     * (1.0f / (float)T_SEQ);
    const float w11 = sd[cp + 1] * (1.0f / (float)T_SEQ);
    const float u10 = sf[cp]     * (1.0f / (float)T_SEQ);
    const float u11 = sf[cp + 1] * (1.0f / (float)T_SEQ);
    const size_t base = ((size_t)b * T_SEQ + ch * CHL) * CDIM + cp;
    const uint_t* kp = (const uint_t*)(kb + base);
    uint_t* vp = (uint_t*)(vb + base);
    size_t idx = (size_t)ch * BC + (size_t)b * CDIM + cp;   // even
    float2 pin = *(const float2*)(inP + idx);
    float2 qin = *(const float2*)(inQ + idx);
    float2 oin = *(const float2*)(inO + idx);
    float p0 = pin.x, q0 = qin.x, o0 = oin.x;
    float p1 = pin.y, q1 = qin.y, o1 = oin.y;
    uint_t ku_[CHL];   // packed k (fp16 x2)
    uint_t yu_[CHL];   // packed y (fp16 x2)
#pragma unroll
    for (int i = 0; i < CHL; i++) {
        uint_t ku = kp[(size_t)i * CD2];
        uint_t vu = vp[(size_t)i * CD2];
        ku_[i] = ku;
        float k0 = h2f((ushort_t)(ku & 0xffff)), k1 = h2f((ushort_t)(ku >> 16));
        float v0 = h2f((ushort_t)(vu & 0xffff)), v1 = h2f((ushort_t)(vu >> 16));
        // channel 0
        float uk0 = u10 + k0;
        float no0 = fmaxf(o0, uk0);
        float Ae0 = __expf(o0 - no0), Be0 = __expf(uk0 - no0);
        float y0 = (Ae0 * p0 + Be0 * v0) / (Ae0 * q0 + Be0);
        float wo0 = w10 + o0;
        float nn0 = fmaxf(wo0, k0);
        float A20 = __expf(wo0 - nn0), B20 = __expf(k0 - nn0);
        p0 = A20 * p0 + B20 * v0;  q0 = A20 * q0 + B20;  o0 = nn0;
        // channel 1
        float uk1 = u11 + k1;
        float no1 = fmaxf(o1, uk1);
        float Ae1 = __expf(o1 - no1), Be1 = __expf(uk1 - no1);
        float y1 = (Ae1 * p1 + Be1 * v1) / (Ae1 * q1 + Be1);
        float wo1 = w11 + o1;
        float nn1 = fmaxf(wo1, k1);
        float A21 = __expf(wo1 - nn1), B21 = __expf(k1 - nn1);
        p1 = A21 * p1 + B21 * v1;  q1 = A21 * q1 + B21;  o1 = nn1;
        uint_t yu = (uint_t)f2h(y0) | ((uint_t)f2h(y1) << 16);
        yu_[i] = yu;
        vp[(size_t)i * CD2] = yu;   // overwrite v with y (4B store)
    }
    // pass-2 summary over same rows; raster traversal; uses fp16-rounded y
    // (== what replay1 reads back from vb). STATIC indexing via uniform branch.
    const float w20 = sd[CDIM + cp]     * (1.0f / (float)T_SEQ);
    const float w21 = sd[CDIM + cp + 1] * (1.0f / (float)T_SEQ);
    float p20 = 0.f, q20 = 0.f, o20 = -1e38f;
    float p21 = 0.f, q21 = 0.f, o21 = -1e38f;
#define P2STEP(I)                                                              \
    {                                                                          \
        uint_t ku = ku_[(I)], yu = yu_[(I)];                                   \
        float k0 = h2f((ushort_t)(ku & 0xffff)), k1 = h2f((ushort_t)(ku >> 16)); \
        float y0 = h2f((ushort_t)(yu & 0xffff)), y1 = h2f((ushort_t)(yu >> 16)); \
        float wo0 = w20 + o20, wo1 = w21 + o21;                                \
        float nn0 = fmaxf(wo0, k0), nn1 = fmaxf(wo1, k1);                      \
        float A20 = __expf(wo0 - nn0), B20 = __expf(k0 - nn0);                 \
        float A21 = __expf(wo1 - nn1), B21 = __expf(k1 - nn1);                 \
        p20 = A20 * p20 + B20 * y0;  q20 = A20 * q20 + B20;  o20 = nn0;        \
        p21 = A21 * p21 + B21 * y1;  q21 = A21 * q21 + B21;  o21 = nn1;        \
    }
    if (((ch >> 1) & 1) == 0) {
#pragma unroll
        for (int j = 0; j < CHL; j++) P2STEP(j)
    } else {
#pragma unroll
        for (int j = 0; j < CHL; j++) P2STEP(CHL - 1 - j)
    }
#undef P2STEP
    size_t idx2 = (size_t)((ch & 2) ? (ch ^ 1) : ch) * BC + (size_t)b * CDIM + cp;
    *(float2*)(sumP + idx2) = make_float2(p20, p21);
    *(float2*)(sumQ + idx2) = make_float2(q20, q21);
    *(float2*)(sumO + idx2) = make_float2(o20, o21);
}

// Phase C (pass 1): replay raster-order chunk ch, emit a2 = bf16(y * sr).
// 2 ch/thread packed loads/stores.
__global__ __launch_bounds__(256) void wkv_replay1(
    const ushort_t* __restrict__ kb, const ushort_t* __restrict__ vb,
    const ushort_t* __restrict__ srb, ushort_t* __restrict__ a2,
    const float* __restrict__ sd, const float* __restrict__ sf,
    const float* __restrict__ inP, const float* __restrict__ inQ,
    const float* __restrict__ inO) {
    int gid = blockIdx.x * 256 + threadIdx.x;   // over NCH*BC2
    int bc2 = gid % BC2;
    int ch  = gid / BC2;
    int b = bc2 / CD2, cp = (bc2 % CD2) * 2;
    const float w0 = sd[CDIM + cp]     * (1.0f / (float)T_SEQ);
    const float w1 = sd[CDIM + cp + 1] * (1.0f / (float)T_SEQ);
    const float u0 = sf[CDIM + cp]     * (1.0f / (float)T_SEQ);
    const float u1 = sf[CDIM + cp + 1] * (1.0f / (float)T_SEQ);
    size_t base = (size_t)b * T_SEQ * CDIM + cp;
    size_t idx = (size_t)ch * BC + (size_t)b * CDIM + cp;   // even
    float2 pin = *(const float2*)(inP + idx);
    float2 qin = *(const float2*)(inQ + idx);
    float2 oin = *(const float2*)(inO + idx);
    float p0 = pin.x, q0 = qin.x, o0 = oin.x;
    float p1 = pin.y, q1 = qin.y, o1 = oin.y;
    const int r = ch >> 1;
    const int pos0 = (ch & 1) * CHL;
#pragma unroll 8
    for (int i = 0; i < CHL; i++) {
        int pos = pos0 + i;
        int col = (r & 1) ? (63 - pos) : pos;
        size_t off = base + (size_t)(r * 64 + col) * CDIM;
        uint_t ku = *(const uint_t*)(kb + off);
        uint_t vu = *(const uint_t*)(vb + off);
        uint_t su = *(const uint_t*)(srb + off);
        float k0 = h2f((ushort_t)(ku & 0xffff)), k1 = h2f((ushort_t)(ku >> 16));
        float v0 = h2f((ushort_t)(vu & 0xffff)), v1 = h2f((ushort_t)(vu >> 16));
        // channel 0
        float uk0 = u0 + k0;
        float no0 = fmaxf(o0, uk0);
        float Ae0 = __expf(o0 - no0), Be0 = __expf(uk0 - no0);
        float y0 = (Ae0 * p0 + Be0 * v0) / (Ae0 * q0 + Be0);
        float wo0 = w0 + o0;
        float nn0 = fmaxf(wo0, k0);
        float A20 = __expf(wo0 - nn0), B20 = __expf(k0 - nn0);
        p0 = A20 * p0 + B20 * v0;  q0 = A20 * q0 + B20;  o0 = nn0;
        // channel 1
        float uk1 = u1 + k1;
        float no1 = fmaxf(o1, uk1);
        float Ae1 = __expf(o1 - no1), Be1 = __expf(uk1 - no1);
        float y1 = (Ae1 * p1 + Be1 * v1) / (Ae1 * q1 + Be1);
        float wo1 = w1 + o1;
        float nn1 = fmaxf(wo1, k1);
        float A21 = __expf(wo1 - nn1), B21 = __expf(k1 - nn1);
        p1 = A21 * p1 + B21 * v1;  q1 = A21 * q1 + B21;  o1 = nn1;
        uint_t out = (uint_t)f2b(y0 * b2f((ushort_t)(su & 0xffff))) |
                     ((uint_t)f2b(y1 * b2f((ushort_t)(su >> 16))) << 16);
        *(uint_t*)(a2 + off) = out;
    }
}

// ----------------------------------------------------------------------- launch
extern "C" void kernel_launch(void* const* d_in, const int* in_sizes, int n_in,
                              void* d_out, int out_size, void* d_ws, size_t ws_size,
                              hipStream_t stream) {
    (void)in_sizes; (void)n_in; (void)out_size; (void)ws_size;
    const float* x  = (const float*)d_in[0];
    const float* kw = (const float*)d_in[1];
    const float* vw = (const float*)d_in[2];
    const float* rw = (const float*)d_in[3];
    const float* ow = (const float*)d_in[4];
    const float* sd = (const float*)d_in[5];
    const float* sf = (const float*)d_in[6];
    float* out = (float*)d_out;

    char* ws = (char*)d_ws;
    size_t off = 0;
    auto alloc = [&](size_t bytes) -> void* {
        void* p = ws + off;
        off += (bytes + 255) & ~(size_t)255;
        return p;
    };
    ushort_t* xs   = (ushort_t*)alloc((size_t)MROWS * CDIM * 2);  // reused as a2
    ushort_t* kb   = (ushort_t*)alloc((size_t)MROWS * CDIM * 2);  // k fp16
    ushort_t* vb   = (ushort_t*)alloc((size_t)MROWS * CDIM * 2);  // v / y fp16
    ushort_t* srb  = (ushort_t*)alloc((size_t)MROWS * CDIM * 2);  // bf16
    ushort_t* wkvr = (ushort_t*)alloc((size_t)NKVR * CDIM * 2);
    ushort_t* wo   = (ushort_t*)alloc((size_t)CDIM * CDIM * 2);
    float*    sumP = (float*)   alloc((size_t)NCH * BC * 4);
    float*    sumQ = (float*)   alloc((size_t)NCH * BC * 4);
    float*    sumO = (float*)   alloc((size_t)NCH * BC * 4);
    float*    inP  = (float*)   alloc((size_t)NCH * BC * 4);
    float*    inQ  = (float*)   alloc((size_t)NCH * BC * 4);
    float*    inO  = (float*)   alloc((size_t)NCH * BC * 4);

    cvt_weights<<<(CDIM * CDIM + 255) / 256, 256, 0, stream>>>(kw, vw, rw, ow, wkvr, wo);
    shift_zigzag<<<(int)((size_t)MROWS * (CDIM / 8) / 256), 256, 0, stream>>>(x, xs);
    gemm_kvr<<<(MROWS / 128) * (NKVR / 128), 256, 0, stream>>>(
        xs, wkvr, kb, vb, srb);

    const int nwkv2 = NCH * BC2;  // 393216 threads (2-ch kernels)
    wkv_chunk_sum0<<<nwkv2 / 256, 256, 0, stream>>>(kb, vb, sd, sumP, sumQ, sumO);
    wkv_chunk_scan<<<(BC + 255) / 256, 256, 0, stream>>>(sumP, sumQ, sumO,
                                                         inP, inQ, inO, sd, 0);
    wkv_replay0_sum1<<<nwkv2 / 256, 256, 0, stream>>>(kb, vb, sd, sf,
                                                      inP, inQ, inO, sumP, sumQ, sumO);
    wkv_chunk_scan<<<(BC + 255) / 256, 256, 0, stream>>>(sumP, sumQ, sumO,
                                                         inP, inQ, inO, sd, 1);
    wkv_replay1<<<nwkv2 / 256, 256, 0, stream>>>(kb, vb, srb, xs,
                                                 sd, sf, inP, inQ, inO);

    gemm_out<<<(MROWS / 128) * (CDIM / 128), 256, 0, stream>>>(xs, wo, out);
}